// Round 8
// baseline (168.895 us; speedup 1.0000x reference)
//
#include <hip/hip_runtime.h>
#include <hip/hip_bf16.h>

// Segment-sum via fixed-capacity direct CSR + atomic-free gather.
// out[seg, f] = sum over edges e with edge[row][e]==seg of edge_w[e, f].
// row = 0 if dim==1 else 1 (read on device).
//
// R7: build collapsed to ONE atomic pass. deg ~ Poisson(25) (max ~58), so
// perm_fixed[seg*64 + rank] = e written directly during the histogram
// (rank = atomicAdd(&counts[seg],1)). Deletes scanA/scanBC/place and the
// rank array (10MB I/O + 2 launch gaps). Edges with rank >= 64 (none for
// this input, but handled unconditionally) go to an overflow list consumed
// by a post-gather atomic fixup kernel. Gather loop identical to R6.

#define F_DIM 64
#define CAP 64        // per-node slot capacity; Poisson(25) max deg << 64
#define CAPLOG 6

typedef __attribute__((ext_vector_type(4))) float f4v;

// ---------- zero counts + overflow counter ----------
__global__ void zero_kernel(int* __restrict__ p, int n) {
    const int i = blockIdx.x * blockDim.x + threadIdx.x;
    if (i < n) p[i] = 0;
}

// ---------- build: one atomic pass writes the fixed-capacity CSR ----------
__global__ void build_kernel(const int* __restrict__ edge,
                             const int* __restrict__ dim_p,
                             int* __restrict__ counts,
                             int* __restrict__ perm_fixed,
                             int* __restrict__ ovf,
                             int* __restrict__ ovf_cnt, int E) {
    const int row = (*dim_p == 1) ? 0 : 1;
    const int* er = edge + (size_t)row * E;
    const int stride = gridDim.x * blockDim.x;
    if ((E & 3) == 0) {
        const int nvec = E >> 2;
        const int4* er4 = reinterpret_cast<const int4*>(er);
        for (int v = blockIdx.x * blockDim.x + threadIdx.x; v < nvec; v += stride) {
            const int4 ev = er4[v];
            const int e = v << 2;
            int rk;
            rk = atomicAdd(&counts[ev.x], 1);
            if (rk < CAP) perm_fixed[(ev.x << CAPLOG) + rk] = e + 0;
            else ovf[atomicAdd(ovf_cnt, 1)] = e + 0;
            rk = atomicAdd(&counts[ev.y], 1);
            if (rk < CAP) perm_fixed[(ev.y << CAPLOG) + rk] = e + 1;
            else ovf[atomicAdd(ovf_cnt, 1)] = e + 1;
            rk = atomicAdd(&counts[ev.z], 1);
            if (rk < CAP) perm_fixed[(ev.z << CAPLOG) + rk] = e + 2;
            else ovf[atomicAdd(ovf_cnt, 1)] = e + 2;
            rk = atomicAdd(&counts[ev.w], 1);
            if (rk < CAP) perm_fixed[(ev.w << CAPLOG) + rk] = e + 3;
            else ovf[atomicAdd(ovf_cnt, 1)] = e + 3;
        }
    } else {
        for (int e = blockIdx.x * blockDim.x + threadIdx.x; e < E; e += stride) {
            const int seg = er[e];
            const int rk = atomicAdd(&counts[seg], 1);
            if (rk < CAP) perm_fixed[(seg << CAPLOG) + rk] = e;
            else ovf[atomicAdd(ovf_cnt, 1)] = e;
        }
    }
}

// ---------- gather-reduce: one wave per node (R6 inner loop) ----------
// 8 groups of 8 lanes; group g handles slots beg+g, +8, +16, +24.
// 4-deep predicated unroll; invalid slots clamp to slot0 (L1-hit dup).
__global__ __launch_bounds__(256) void gather_kernel(
    const float* __restrict__ edge_w,
    const int* __restrict__ counts,
    const int* __restrict__ perm_fixed,
    float* __restrict__ out, int N) {
    const int node = blockIdx.x * 4 + (threadIdx.x >> 6);
    const int lane = threadIdx.x & 63;
    if (node >= N) return;
    const int cnt = counts[node];
    const int beg = node << CAPLOG;
    const int end = beg + (cnt < CAP ? cnt : CAP);
    const int grp = lane >> 3;            // 0..7 : edge slot in the 8-batch
    const int sub = (lane & 7) << 3;      // feature offset 0..56 step 8
    f4v a0 = 0.0f, a1 = 0.0f;
    int j = beg + grp;
    while (j < end) {
        const int j1 = j + 8, j2 = j + 16, j3 = j + 24;
        const int e0 = perm_fixed[j];
        const int e1 = (j1 < end) ? perm_fixed[j1] : e0;
        const int e2 = (j2 < end) ? perm_fixed[j2] : e0;
        const int e3 = (j3 < end) ? perm_fixed[j3] : e0;
        const f4v* p0 = reinterpret_cast<const f4v*>(edge_w + (size_t)e0 * F_DIM + sub);
        const f4v* p1 = reinterpret_cast<const f4v*>(edge_w + (size_t)e1 * F_DIM + sub);
        const f4v* p2 = reinterpret_cast<const f4v*>(edge_w + (size_t)e2 * F_DIM + sub);
        const f4v* p3 = reinterpret_cast<const f4v*>(edge_w + (size_t)e3 * F_DIM + sub);
        const f4v u0 = p0[0], u1 = p0[1];
        const f4v v0 = p1[0], v1 = p1[1];
        const f4v w0 = p2[0], w1 = p2[1];
        const f4v x0 = p3[0], x1 = p3[1];
        a0 += u0; a1 += u1;
        if (j1 < end) { a0 += v0; a1 += v1; }
        if (j2 < end) { a0 += w0; a1 += w1; }
        if (j3 < end) { a0 += x0; a1 += x1; }
        j += 32;
    }
    #pragma unroll
    for (int m = 8; m < 64; m <<= 1) {
        a0.x += __shfl_xor(a0.x, m); a0.y += __shfl_xor(a0.y, m);
        a0.z += __shfl_xor(a0.z, m); a0.w += __shfl_xor(a0.w, m);
        a1.x += __shfl_xor(a1.x, m); a1.y += __shfl_xor(a1.y, m);
        a1.z += __shfl_xor(a1.z, m); a1.w += __shfl_xor(a1.w, m);
    }
    if (grp == 0) {
        float* o = out + (size_t)node * F_DIM + sub;
        *reinterpret_cast<f4v*>(o)     = a0;
        *reinterpret_cast<f4v*>(o + 4) = a1;
    }
}

// ---------- fixup: atomically add overflow edges (expected 0 entries) ----------
__global__ void fixup_kernel(const int* __restrict__ edge,
                             const int* __restrict__ dim_p,
                             const float* __restrict__ edge_w,
                             const int* __restrict__ ovf,
                             const int* __restrict__ ovf_cnt,
                             float* __restrict__ out, int E) {
    const int n = *ovf_cnt;
    if (n == 0) return;
    const int row = (*dim_p == 1) ? 0 : 1;
    const long long total = (long long)n * 16;
    const long long stride = (long long)gridDim.x * blockDim.x;
    for (long long i = (long long)blockIdx.x * blockDim.x + threadIdx.x;
         i < total; i += stride) {
        const int e = ovf[(int)(i >> 4)];
        const int c = ((int)i & 15) << 2;
        const int seg = edge[(size_t)row * E + e];
        const float4 v = *reinterpret_cast<const float4*>(
            edge_w + (size_t)e * F_DIM + c);
        float* o = out + (size_t)seg * F_DIM + c;
        atomicAdd(o + 0, v.x);
        atomicAdd(o + 1, v.y);
        atomicAdd(o + 2, v.z);
        atomicAdd(o + 3, v.w);
    }
}

// ---------- fallback: direct atomic scatter ----------
__global__ void atomic_kernel(const int* __restrict__ edge,
                              const float* __restrict__ edge_w,
                              const int* __restrict__ dim_p,
                              float* __restrict__ out, int E) {
    const int row = (*dim_p == 1) ? 0 : 1;
    const long long total = (long long)E * 16;
    const long long stride = (long long)gridDim.x * blockDim.x;
    for (long long i = (long long)blockIdx.x * blockDim.x + threadIdx.x;
         i < total; i += stride) {
        const int e = (int)(i >> 4);
        const int c = ((int)i & 15) << 2;
        const int seg = edge[(long long)row * E + e];
        const float4 v = *reinterpret_cast<const float4*>(
            edge_w + (long long)e * F_DIM + c);
        float* o = out + (long long)seg * F_DIM + c;
        atomicAdd(o + 0, v.x);
        atomicAdd(o + 1, v.y);
        atomicAdd(o + 2, v.z);
        atomicAdd(o + 3, v.w);
    }
}

extern "C" void kernel_launch(void* const* d_in, const int* in_sizes, int n_in,
                              void* d_out, int out_size, void* d_ws, size_t ws_size,
                              hipStream_t stream) {
    const int*   edge   = (const int*)d_in[0];
    const float* edge_w = (const float*)d_in[1];
    const int*   dim_p  = (const int*)d_in[5];
    float*       out    = (float*)d_out;

    const int E = in_sizes[0] / 2;
    const int F = in_sizes[1] / E;           // 64
    const int N = out_size / F;              // 50000

    // ws: counts[N] | ovf_cnt[1] | perm_fixed[N*CAP] | ovf[E]
    const size_t need = ((size_t)N + 1 + ((size_t)N << CAPLOG) + (size_t)E) * sizeof(int);
    if (ws_size < need) {
        hipMemsetAsync(d_out, 0, (size_t)out_size * sizeof(float), stream);
        atomic_kernel<<<2048, 256, 0, stream>>>(edge, edge_w, dim_p, out, E);
        return;
    }

    int* counts     = (int*)d_ws;
    int* ovf_cnt    = counts + N;
    int* perm_fixed = ovf_cnt + 1;
    int* ovf        = perm_fixed + ((size_t)N << CAPLOG);

    const int block = 256;
    const int gridZ = (N + 1 + block - 1) / block;            // zero counts+ovf_cnt
    const int gridB = (E & 3) ? (E + block - 1) / block
                              : (E / 4 + block - 1) / block;  // build (vec4)
    const int gridN = (N + 3) / 4;                            // 4 waves/block

    zero_kernel<<<gridZ, block, 0, stream>>>(counts, N + 1);
    build_kernel<<<(gridB > 4096 ? 4096 : gridB), block, 0, stream>>>(
        edge, dim_p, counts, perm_fixed, ovf, ovf_cnt, E);
    gather_kernel<<<gridN, block, 0, stream>>>(edge_w, counts, perm_fixed, out, N);
    fixup_kernel<<<64, block, 0, stream>>>(edge, dim_p, edge_w, ovf, ovf_cnt, out, E);
}

// Round 9
// 149.236 us; speedup vs baseline: 1.1317x; 1.1317x over previous
//
#include <hip/hip_runtime.h>
#include <hip/hip_bf16.h>

// Segment-sum via CSR build + atomic-free gather.
// out[seg, f] = sum over edges e with edge[row][e]==seg of edge_w[e, f].
// row = 0 if dim==1 else 1 (read on device).
//
// R8: revert to R6 structure (R7's fused fixed-cap build regressed +17us:
// scattered store data-dependent on atomic return). Single change vs R6:
// replica index r = blockIdx.x & 7 (~XCD id under round-robin dispatch)
// instead of (e>>8)&7, so each counts replica stays in ONE XCD's L2 --
// attacks cross-XCD cache-line migration of device-scope atomics.
// r is packed into rank's high bits (rank < 2^21), unpacked by place, so
// correctness holds for ANY per-edge r. Gather byte-identical to R6.

#define F_DIM 64

typedef __attribute__((ext_vector_type(4))) float f4v;

// ---------- zero counts ----------
__global__ void zero_kernel(int* __restrict__ p, int n) {
    const int i = blockIdx.x * blockDim.x + threadIdx.x;
    if (i < n) p[i] = 0;
}

// ---------- rank-histogram: counts8[r*N+seg]++, rank[e] = old | r<<24 ----------
template <int R>
__global__ void rank_hist_kernel(const int* __restrict__ edge,
                                 const int* __restrict__ dim_p,
                                 int* __restrict__ counts8,
                                 int* __restrict__ rank, int E, int N) {
    const int row = (*dim_p == 1) ? 0 : 1;
    const int* er = edge + (size_t)row * E;
    const int stride = gridDim.x * blockDim.x;
    const int r = blockIdx.x & (R - 1);          // ~XCD-local replica
    int* cb = counts8 + (size_t)r * N;
    const int rtag = r << 24;
    if ((E & 3) == 0) {
        const int nvec = E >> 2;
        const int4* er4 = reinterpret_cast<const int4*>(er);
        int4* rank4 = reinterpret_cast<int4*>(rank);
        for (int v = blockIdx.x * blockDim.x + threadIdx.x; v < nvec; v += stride) {
            const int4 ev = er4[v];
            int4 rk;
            rk.x = atomicAdd(&cb[ev.x], 1) | rtag;
            rk.y = atomicAdd(&cb[ev.y], 1) | rtag;
            rk.z = atomicAdd(&cb[ev.z], 1) | rtag;
            rk.w = atomicAdd(&cb[ev.w], 1) | rtag;
            rank4[v] = rk;
        }
    } else {
        for (int e = blockIdx.x * blockDim.x + threadIdx.x; e < E; e += stride)
            rank[e] = atomicAdd(&cb[er[e]], 1) | rtag;
    }
}

// ---------- scan A: fold replicas, per-block scan, replica prefixes ----------
template <int R>
__global__ void scanA_kernel(int* __restrict__ counts8,
                             int* __restrict__ offsets,
                             int* __restrict__ partials, int N) {
    __shared__ int s[256];
    const int t = threadIdx.x;
    const int idx = blockIdx.x * 256 + t;
    int c[R];
    int tot = 0;
    if (idx < N) {
        #pragma unroll
        for (int r = 0; r < R; ++r) { c[r] = counts8[(size_t)r * N + idx]; tot += c[r]; }
    }
    s[t] = tot;
    __syncthreads();
    for (int d = 1; d < 256; d <<= 1) {
        const int x = (t >= d) ? s[t - d] : 0;
        __syncthreads();
        s[t] += x;
        __syncthreads();
    }
    if (idx < N) {
        offsets[idx] = s[t] - tot;              // block-local exclusive
        int run = 0;
        #pragma unroll
        for (int r = 0; r < R; ++r) {           // per-replica exclusive prefix
            counts8[(size_t)r * N + idx] = run;
            run += c[r];
        }
    }
    if (t == 255) partials[blockIdx.x] = s[255];
}

// ---------- scan BC: each block scans all partials in LDS, applies ----------
__global__ void scanBC_kernel(int* __restrict__ offsets,
                              const int* __restrict__ partials,
                              int N, int E, int NB) {
    __shared__ int s[256];
    const int t = threadIdx.x;
    const int v = (t < NB) ? partials[t] : 0;
    s[t] = v;
    __syncthreads();
    for (int d = 1; d < 256; d <<= 1) {
        const int x = (t >= d) ? s[t - d] : 0;
        __syncthreads();
        s[t] += x;
        __syncthreads();
    }
    const int prefix = s[blockIdx.x] - ((blockIdx.x < NB) ? partials[blockIdx.x] : 0);
    const int idx = blockIdx.x * 256 + t;
    if (idx < N) offsets[idx] += prefix;
    if (idx == 0) offsets[N] = E;
}

// ---------- place: perm[offsets[seg]+replicaPrefix+rank] = e ----------
template <int R>
__global__ void place_kernel(const int* __restrict__ edge,
                             const int* __restrict__ dim_p,
                             const int* __restrict__ offsets,
                             const int* __restrict__ counts8,  // replica prefixes
                             const int* __restrict__ rank,
                             int* __restrict__ perm, int E, int N) {
    const int row = (*dim_p == 1) ? 0 : 1;
    const int* er = edge + (size_t)row * E;
    const int stride = gridDim.x * blockDim.x;
    if ((E & 3) == 0) {
        const int nvec = E >> 2;
        const int4* er4 = reinterpret_cast<const int4*>(er);
        const int4* rank4 = reinterpret_cast<const int4*>(rank);
        for (int v = blockIdx.x * blockDim.x + threadIdx.x; v < nvec; v += stride) {
            const int4 ev = er4[v];
            const int4 rk = rank4[v];
            const int e = v << 2;
            perm[offsets[ev.x] + counts8[(size_t)((rk.x >> 24) & (R - 1)) * N + ev.x]
                 + (rk.x & 0xFFFFFF)] = e + 0;
            perm[offsets[ev.y] + counts8[(size_t)((rk.y >> 24) & (R - 1)) * N + ev.y]
                 + (rk.y & 0xFFFFFF)] = e + 1;
            perm[offsets[ev.z] + counts8[(size_t)((rk.z >> 24) & (R - 1)) * N + ev.z]
                 + (rk.z & 0xFFFFFF)] = e + 2;
            perm[offsets[ev.w] + counts8[(size_t)((rk.w >> 24) & (R - 1)) * N + ev.w]
                 + (rk.w & 0xFFFFFF)] = e + 3;
        }
    } else {
        for (int e = blockIdx.x * blockDim.x + threadIdx.x; e < E; e += stride) {
            const int seg = er[e];
            const int rk = rank[e];
            perm[offsets[seg] + counts8[(size_t)((rk >> 24) & (R - 1)) * N + seg]
                 + (rk & 0xFFFFFF)] = e;
        }
    }
}

// ---------- gather-reduce: one wave per node (identical to R6) ----------
__global__ __launch_bounds__(256) void gather_kernel(
    const float* __restrict__ edge_w,
    const int* __restrict__ offsets,
    const int* __restrict__ perm,
    float* __restrict__ out, int N) {
    const int node = blockIdx.x * 4 + (threadIdx.x >> 6);
    const int lane = threadIdx.x & 63;
    if (node >= N) return;
    const int beg = offsets[node];
    const int end = offsets[node + 1];
    const int grp = lane >> 3;            // 0..7 : edge slot in the 8-batch
    const int sub = (lane & 7) << 3;      // feature offset 0..56 step 8
    f4v a0 = 0.0f, a1 = 0.0f;
    int j = beg + grp;
    while (j < end) {
        const int j1 = j + 8, j2 = j + 16, j3 = j + 24;
        const int e0 = perm[j];
        const int e1 = (j1 < end) ? perm[j1] : e0;
        const int e2 = (j2 < end) ? perm[j2] : e0;
        const int e3 = (j3 < end) ? perm[j3] : e0;
        const f4v* p0 = reinterpret_cast<const f4v*>(edge_w + (size_t)e0 * F_DIM + sub);
        const f4v* p1 = reinterpret_cast<const f4v*>(edge_w + (size_t)e1 * F_DIM + sub);
        const f4v* p2 = reinterpret_cast<const f4v*>(edge_w + (size_t)e2 * F_DIM + sub);
        const f4v* p3 = reinterpret_cast<const f4v*>(edge_w + (size_t)e3 * F_DIM + sub);
        const f4v u0 = p0[0], u1 = p0[1];
        const f4v v0 = p1[0], v1 = p1[1];
        const f4v w0 = p2[0], w1 = p2[1];
        const f4v x0 = p3[0], x1 = p3[1];
        a0 += u0; a1 += u1;
        if (j1 < end) { a0 += v0; a1 += v1; }
        if (j2 < end) { a0 += w0; a1 += w1; }
        if (j3 < end) { a0 += x0; a1 += x1; }
        j += 32;
    }
    #pragma unroll
    for (int m = 8; m < 64; m <<= 1) {
        a0.x += __shfl_xor(a0.x, m); a0.y += __shfl_xor(a0.y, m);
        a0.z += __shfl_xor(a0.z, m); a0.w += __shfl_xor(a0.w, m);
        a1.x += __shfl_xor(a1.x, m); a1.y += __shfl_xor(a1.y, m);
        a1.z += __shfl_xor(a1.z, m); a1.w += __shfl_xor(a1.w, m);
    }
    if (grp == 0) {
        float* o = out + (size_t)node * F_DIM + sub;
        *reinterpret_cast<f4v*>(o)     = a0;
        *reinterpret_cast<f4v*>(o + 4) = a1;
    }
}

// ---------- fallback: direct atomic scatter ----------
__global__ void atomic_kernel(const int* __restrict__ edge,
                              const float* __restrict__ edge_w,
                              const int* __restrict__ dim_p,
                              float* __restrict__ out, int E) {
    const int row = (*dim_p == 1) ? 0 : 1;
    const long long total = (long long)E * 16;
    const long long stride = (long long)gridDim.x * blockDim.x;
    for (long long i = (long long)blockIdx.x * blockDim.x + threadIdx.x;
         i < total; i += stride) {
        const int e = (int)(i >> 4);
        const int c = ((int)i & 15) << 2;
        const int seg = edge[(long long)row * E + e];
        const float4 v = *reinterpret_cast<const float4*>(
            edge_w + (long long)e * F_DIM + c);
        float* o = out + (long long)seg * F_DIM + c;
        atomicAdd(o + 0, v.x);
        atomicAdd(o + 1, v.y);
        atomicAdd(o + 2, v.z);
        atomicAdd(o + 3, v.w);
    }
}

extern "C" void kernel_launch(void* const* d_in, const int* in_sizes, int n_in,
                              void* d_out, int out_size, void* d_ws, size_t ws_size,
                              hipStream_t stream) {
    const int*   edge   = (const int*)d_in[0];
    const float* edge_w = (const float*)d_in[1];
    const int*   dim_p  = (const int*)d_in[5];
    float*       out    = (float*)d_out;

    const int E = in_sizes[0] / 2;
    const int F = in_sizes[1] / E;           // 64
    const int N = out_size / F;              // 50000
    const int NB = (N + 255) / 256;          // scan blocks (196)

    // ws: counts8[R*N] | offsets[N+1] | perm[E] | partials[256]; rank in d_out
    const size_t need8 = ((size_t)8 * N + N + 1 + (size_t)E + 256) * sizeof(int);
    const size_t need1 = ((size_t)1 * N + N + 1 + (size_t)E + 256) * sizeof(int);
    const bool rank_fits = (size_t)E <= (size_t)out_size;
    if (ws_size < need1 || NB > 256 || !rank_fits) {
        hipMemsetAsync(d_out, 0, (size_t)out_size * sizeof(float), stream);
        atomic_kernel<<<2048, 256, 0, stream>>>(edge, edge_w, dim_p, out, E);
        return;
    }
    const int R = (ws_size >= need8) ? 8 : 1;

    int* counts8  = (int*)d_ws;
    int* offsets  = counts8 + (size_t)R * N;
    int* perm     = offsets + N + 1;
    int* partials = perm + E;
    int* rank     = (int*)d_out;             // scratch; overwritten by gather

    const int block = 256;
    const int gridV = min(4096, (E / 4 + block - 1) / block);  // vec4 grids
    const int gridE = min(4096, (E + block - 1) / block);
    const int gridZ = (R * N + block - 1) / block;

    zero_kernel<<<gridZ, block, 0, stream>>>(counts8, R * N);
    if (R == 8) {
        rank_hist_kernel<8><<<(E & 3) ? gridE : gridV, block, 0, stream>>>(
            edge, dim_p, counts8, rank, E, N);
        scanA_kernel<8><<<NB, block, 0, stream>>>(counts8, offsets, partials, N);
        scanBC_kernel<<<NB, block, 0, stream>>>(offsets, partials, N, E, NB);
        place_kernel<8><<<(E & 3) ? gridE : gridV, block, 0, stream>>>(
            edge, dim_p, offsets, counts8, rank, perm, E, N);
    } else {
        rank_hist_kernel<1><<<(E & 3) ? gridE : gridV, block, 0, stream>>>(
            edge, dim_p, counts8, rank, E, N);
        scanA_kernel<1><<<NB, block, 0, stream>>>(counts8, offsets, partials, N);
        scanBC_kernel<<<NB, block, 0, stream>>>(offsets, partials, N, E, NB);
        place_kernel<1><<<(E & 3) ? gridE : gridV, block, 0, stream>>>(
            edge, dim_p, offsets, counts8, rank, perm, E, N);
    }

    const int gridN = (N + 3) / 4;           // 4 nodes (waves) per block
    gather_kernel<<<gridN, block, 0, stream>>>(edge_w, offsets, perm, out, N);
}